// Round 3
// baseline (930.336 us; speedup 1.0000x reference)
//
#include <hip/hip_runtime.h>

// Problem constants (match reference)
#define NX_ 432
#define NY_ 496
#define C_  64
#define B_  4
#define CELLS_ (NX_ * NY_)            // 214272 cells per (bin, batch) canvas plane
#define PLANE_ ((size_t)CELLS_)       // c-plane stride in floats
#define BATCH_STRIDE_ ((size_t)C_ * CELLS_)        // 13,713,408 floats
#define BIN_STRIDE_   ((size_t)B_ * C_ * CELLS_)   // 54,853,632 floats
#define MAP_BIN_ ((size_t)B_ * CELLS_)             // map entries per bin

typedef float vfloat4 __attribute__((ext_vector_type(4)));
typedef int   vint4   __attribute__((ext_vector_type(4)));

// ---------------------------------------------------------------------------
// Kernel 1: scatter pillar index p into map[bin][b*CELLS + z + y*NX + x]
// coords layout per row: [b, z, y, x] int32. Cells are unique per sample.
// ---------------------------------------------------------------------------
__global__ __launch_bounds__(256) void scatter_idx_kernel(
    const int* __restrict__ coords0,
    const int* __restrict__ coords1,
    const int* __restrict__ coords2,
    int* __restrict__ map, int npil)
{
    const int bin = blockIdx.y;
    const int p = blockIdx.x * 256 + threadIdx.x;
    if (p >= npil) return;
    const int* coords = (bin == 0) ? coords0 : (bin == 1) ? coords1 : coords2;
    vint4 c = ((const vint4*)coords)[p];
    size_t idx = (size_t)bin * MAP_BIN_ + (size_t)c.x * CELLS_ + c.y + c.z * NX_ + c.w;
    map[idx] = p;
}

// ---------------------------------------------------------------------------
// Kernel 2 (round 3): PLANE-MAJOR gather. One block per (bin, b, c-plane);
// the block streams its entire 857 KB output plane CONTIGUOUSLY in 4 KB
// steps — the same store shape as the harness's fillBuffer, which sustains
// 6.2 TB/s on this machine. This replaces the previous cell-major layout
// whose concurrent store set was scattered 4 KB chunks across 768 planes
// (waves drift on gather latency -> poor DRAM row/page coherence).
//
// Reads per block: map slice re-read (L2-resident, ~857 KB/(bin,b)) and
// pf column gathers (4 B per valid lane; invalid lanes clamp to row 0 =
// same cache line, effectively broadcast). Map load for iteration i+1 is
// prefetched during iteration i.
// ---------------------------------------------------------------------------
__global__ __launch_bounds__(256) void gather_plane_kernel(
    const float* __restrict__ pf0,
    const float* __restrict__ pf1,
    const float* __restrict__ pf2,
    const int* __restrict__ map,
    float* __restrict__ out)
{
    const int c   = blockIdx.x;   // 0..63  (feature plane)
    const int b   = blockIdx.y;   // 0..3
    const int bin = blockIdx.z;   // 0..2

    const float* __restrict__ pfb = (bin == 0) ? pf0 : (bin == 1) ? pf1 : pf2;
    const float* __restrict__ pfc = pfb + c;        // column base: row stride C_

    const int* __restrict__ m = map + (size_t)bin * MAP_BIN_ + (size_t)b * CELLS_;
    float* __restrict__ o = out + (size_t)bin * BIN_STRIDE_
                                + (size_t)b * BATCH_STRIDE_
                                + (size_t)c * PLANE_;

    int cell = threadIdx.x * 4;                      // < 1024 <= CELLS_: safe
    vint4 idx = *(const vint4*)(m + cell);           // prefetch iter 0

    while (cell < CELLS_) {
        const int next = cell + 1024;                // 4 KB block stride
        vint4 nidx;
        if (next < CELLS_)                           // guarded prefetch (tail)
            nidx = *(const vint4*)(m + next);

        // Clamp invalid (-1) to row 0 -> always-safe broadcast line; load
        // unconditionally (no exec-mask branch), select zero after.
        const int i0 = idx.x, i1 = idx.y, i2 = idx.z, i3 = idx.w;
        float x0 = pfc[(size_t)(i0 >= 0 ? i0 : 0) * C_];
        float x1 = pfc[(size_t)(i1 >= 0 ? i1 : 0) * C_];
        float x2 = pfc[(size_t)(i2 >= 0 ? i2 : 0) * C_];
        float x3 = pfc[(size_t)(i3 >= 0 ? i3 : 0) * C_];

        vfloat4 w;
        w.x = i0 >= 0 ? x0 : 0.0f;
        w.y = i1 >= 0 ? x1 : 0.0f;
        w.z = i2 >= 0 ? x2 : 0.0f;
        w.w = i3 >= 0 ? x3 : 0.0f;
        *(vfloat4*)(o + cell) = w;

        cell = next;
        idx = nidx;
    }
}

extern "C" void kernel_launch(void* const* d_in, const int* in_sizes, int n_in,
                              void* d_out, int out_size, void* d_ws, size_t ws_size,
                              hipStream_t stream) {
    const float* pf0 = (const float*)d_in[0];
    const int*   co0 = (const int*)d_in[1];
    const float* pf1 = (const float*)d_in[2];
    const int*   co1 = (const int*)d_in[3];
    const float* pf2 = (const float*)d_in[4];
    const int*   co2 = (const int*)d_in[5];
    float* out = (float*)d_out;

    const int npil = in_sizes[1] / 4;   // rows in coords (B*P_PER)

    int* map = (int*)d_ws;
    const size_t map_bytes = 3 * MAP_BIN_ * sizeof(int);

    // init map to -1 (0xFFFFFFFF) — ~10 MB, ~2 us
    (void)hipMemsetAsync(map, 0xFF, map_bytes, stream);

    dim3 g1((npil + 255) / 256, 3, 1);
    scatter_idx_kernel<<<g1, 256, 0, stream>>>(co0, co1, co2, map, npil);

    // plane-major: one block per (c, b, bin) = 64 x 4 x 3 = 768 blocks
    dim3 g2(C_, B_, 3);
    gather_plane_kernel<<<g2, 256, 0, stream>>>(pf0, pf1, pf2, map, out);
}

// Round 4
// 700.850 us; speedup vs baseline: 1.3274x; 1.3274x over previous
//
#include <hip/hip_runtime.h>

// Problem constants (match reference)
#define NX_ 432
#define NY_ 496
#define C_  64
#define B_  4
#define CELLS_ (NX_ * NY_)            // 214272 cells per (bin, batch) canvas plane
#define PLANE_ ((size_t)CELLS_)       // c-plane stride in floats
#define BATCH_STRIDE_ ((size_t)C_ * CELLS_)        // 13,713,408 floats
#define BIN_STRIDE_   ((size_t)B_ * C_ * CELLS_)   // 54,853,632 floats
#define MAP_BIN_ ((size_t)B_ * CELLS_)             // map entries per bin

typedef float vfloat4 __attribute__((ext_vector_type(4)));
typedef int   vint4   __attribute__((ext_vector_type(4)));

// ---------------------------------------------------------------------------
// Kernel 1: scatter pillar index p into map[bin][b*CELLS + z + y*NX + x]
// coords layout per row: [b, z, y, x] int32. Cells are unique per sample.
// ---------------------------------------------------------------------------
__global__ __launch_bounds__(256) void scatter_idx_kernel(
    const int* __restrict__ coords0,
    const int* __restrict__ coords1,
    const int* __restrict__ coords2,
    int* __restrict__ map, int npil)
{
    const int bin = blockIdx.y;
    const int p = blockIdx.x * 256 + threadIdx.x;
    if (p >= npil) return;
    const int* coords = (bin == 0) ? coords0 : (bin == 1) ? coords1 : coords2;
    vint4 c = ((const vint4*)coords)[p];
    size_t idx = (size_t)bin * MAP_BIN_ + (size_t)c.x * CELLS_ + c.y + c.z * NX_ + c.w;
    map[idx] = p;
}

// ---------------------------------------------------------------------------
// Kernel 2 (round 4): cell-major gather with FLOAT4 pillar-row loads + LDS
// transpose. Theory: round-0 (701 us) was bound by scattered-request RATE
// (164M uncoalesceable 4B loads ~= 1 req/cy/CU), not by store BW (r2: NT==
// plain) and not by store locality (r3: dense stores regressed). This
// version loads 16B per request from each thread's own 4 pillar rows
// (4x fewer scattered requests), transposes 4 channels x 1024 cells through
// a 16 KB LDS tile, and stores with the EXACT round-0 pattern (wave w owns
// plane 4g+w; 1 KB contiguous per wave-instruction).
//
// Occupancy: 16 KB LDS, 256 thr -> 8 blocks/CU = 32 waves/CU (full).
// Tail block (base 214016, 256 valid cells): no early return (barriers!);
// map addr clamped, stores predicated per 256-cell chunk.
// ---------------------------------------------------------------------------
__global__ __launch_bounds__(256) void gather_lds_kernel(
    const float* __restrict__ pf0,
    const float* __restrict__ pf1,
    const float* __restrict__ pf2,
    const int* __restrict__ map,
    float* __restrict__ out)
{
    __shared__ float lds[4 * 1024];   // 4 planes x 1024 cells, 16 KB

    const int bin = blockIdx.z;
    const int b   = blockIdx.y;
    const int t   = threadIdx.x;
    const int base = blockIdx.x * 1024;

    const float* __restrict__ pf = (bin == 0) ? pf0 : (bin == 1) ? pf1 : pf2;

    const int cell  = base + t * 4;
    const int mcell = (cell < CELLS_) ? cell : 0;           // clamp map addr (tail)
    const int* m = map + (size_t)bin * MAP_BIN_ + (size_t)b * CELLS_ + mcell;
    vint4 idx = *(const vint4*)m;

    const bool v0 = idx.x >= 0, v1 = idx.y >= 0, v2 = idx.z >= 0, v3 = idx.w >= 0;
    // Clamp invalid to row 0: always-safe address, unconditional loads.
    const float* r0 = pf + (size_t)(v0 ? idx.x : 0) * C_;
    const float* r1 = pf + (size_t)(v1 ? idx.y : 0) * C_;
    const float* r2 = pf + (size_t)(v2 ? idx.z : 0) * C_;
    const float* r3 = pf + (size_t)(v3 ? idx.w : 0) * C_;

    const int wv = t >> 6;    // wave id: which plane of the 4-channel group
    const int ln = t & 63;    // lane
    float* __restrict__ ob = out + (size_t)bin * BIN_STRIDE_
                                 + (size_t)b * BATCH_STRIDE_;

#pragma unroll
    for (int g = 0; g < 16; ++g) {
        // One 16B request per pillar row: channels 4g..4g+3 of own rows.
        vfloat4 x0 = *(const vfloat4*)(r0 + 4 * g);
        vfloat4 x1 = *(const vfloat4*)(r1 + 4 * g);
        vfloat4 x2 = *(const vfloat4*)(r2 + 4 * g);
        vfloat4 x3 = *(const vfloat4*)(r3 + 4 * g);

        __syncthreads();   // prev group's LDS reads complete before overwrite

        // Transpose into plane-major LDS: lds[cc][t*4+q] = x_q[cc].
        // Consecutive q for fixed cc are consecutive floats -> compiler can
        // merge into ds_write_b128 (register transpose).
#pragma unroll
        for (int cc = 0; cc < 4; ++cc) {
            lds[cc * 1024 + t * 4 + 0] = v0 ? x0[cc] : 0.0f;
            lds[cc * 1024 + t * 4 + 1] = v1 ? x1[cc] : 0.0f;
            lds[cc * 1024 + t * 4 + 2] = v2 ? x2[cc] : 0.0f;
            lds[cc * 1024 + t * 4 + 3] = v3 ? x3[cc] : 0.0f;
        }

        __syncthreads();

        // Wave wv stores plane 4g+wv: 4 chunks of 1 KB contiguous (round-0
        // store shape). Predicated per chunk for the tail block.
        float* op = ob + (size_t)(4 * g + wv) * PLANE_;
#pragma unroll
        for (int k = 0; k < 4; ++k) {
            const int oc = ln * 4 + 256 * k;        // 0..1023 within block
            vfloat4 w = *(const vfloat4*)&lds[wv * 1024 + oc];
            if (base + oc < CELLS_)
                *(vfloat4*)(op + base + oc) = w;
        }
    }
}

extern "C" void kernel_launch(void* const* d_in, const int* in_sizes, int n_in,
                              void* d_out, int out_size, void* d_ws, size_t ws_size,
                              hipStream_t stream) {
    const float* pf0 = (const float*)d_in[0];
    const int*   co0 = (const int*)d_in[1];
    const float* pf1 = (const float*)d_in[2];
    const int*   co1 = (const int*)d_in[3];
    const float* pf2 = (const float*)d_in[4];
    const int*   co2 = (const int*)d_in[5];
    float* out = (float*)d_out;

    const int npil = in_sizes[1] / 4;   // rows in coords (B*P_PER)

    int* map = (int*)d_ws;
    const size_t map_bytes = 3 * MAP_BIN_ * sizeof(int);

    // init map to -1 (0xFFFFFFFF) — ~10 MB, ~2 us
    (void)hipMemsetAsync(map, 0xFF, map_bytes, stream);

    dim3 g1((npil + 255) / 256, 3, 1);
    scatter_idx_kernel<<<g1, 256, 0, stream>>>(co0, co1, co2, map, npil);

    dim3 g2((CELLS_ + 1023) / 1024, B_, 3);   // 210 x 4 x 3 blocks
    gather_lds_kernel<<<g2, 256, 0, stream>>>(pf0, pf1, pf2, map, out);
}

// Round 5
// 684.411 us; speedup vs baseline: 1.3593x; 1.0240x over previous
//
#include <hip/hip_runtime.h>

// Problem constants (match reference)
#define NX_ 432
#define NY_ 496
#define C_  64
#define B_  4
#define CELLS_ (NX_ * NY_)            // 214272 cells per (bin, batch) canvas plane
#define PLANE_ ((size_t)CELLS_)       // c-plane stride in floats
#define BATCH_STRIDE_ ((size_t)C_ * CELLS_)        // 13,713,408 floats
#define BIN_STRIDE_   ((size_t)B_ * C_ * CELLS_)   // 54,853,632 floats
#define MAP_BIN_ ((size_t)B_ * CELLS_)             // map entries per bin

typedef float vfloat4 __attribute__((ext_vector_type(4)));
typedef int   vint4   __attribute__((ext_vector_type(4)));

// ---------------------------------------------------------------------------
// Kernel 1: scatter pillar index p into map[bin][b*CELLS + z + y*NX + x]
// coords layout per row: [b, z, y, x] int32. Cells are unique per sample.
// ---------------------------------------------------------------------------
__global__ __launch_bounds__(256) void scatter_idx_kernel(
    const int* __restrict__ coords0,
    const int* __restrict__ coords1,
    const int* __restrict__ coords2,
    int* __restrict__ map, int npil)
{
    const int bin = blockIdx.y;
    const int p = blockIdx.x * 256 + threadIdx.x;
    if (p >= npil) return;
    const int* coords = (bin == 0) ? coords0 : (bin == 1) ? coords1 : coords2;
    vint4 c = ((const vint4*)coords)[p];
    size_t idx = (size_t)bin * MAP_BIN_ + (size_t)c.x * CELLS_ + c.y + c.z * NX_ + c.w;
    map[idx] = p;
}

// ---------------------------------------------------------------------------
// Kernel 2 (round 5): PLANE-GROUP-SPLIT gather — isolates the write-stream
// dispersion variable. Identical to the 701 us round-0 kernel in thread
// mapping, branchless clamped loads, and float4 store shape, EXCEPT the
// 64-channel loop is split across blockIdx.y: each block writes only 4
// planes. With blockIdx.x fastest-varying, the ~2048 co-resident blocks
// write a DENSE ~40 MB advancing frontier (fill-like) instead of scattering
// 4 KB chunks across the whole 658 MB output (all ~701 us variants did the
// latter; the harness fill at 6.2 TB/s does the former).
//
// Read cost of the split: map re-read 16x (160 MB logical) and each pf line
// shared by 4 plane-groups — both L3-resident (10 MB / 49 MB), so HBM
// traffic stays near the 720 MB floor.
//
// Per thread: 1x16B map load, 4x16B pf loads (channels 4g..4g+3 = bytes
// [16g,16g+16) of a pillar row = one aligned float4), 4x16B stores.
// No LDS, no barriers.
// ---------------------------------------------------------------------------
__global__ __launch_bounds__(256) void gather_split_kernel(
    const float* __restrict__ pf0,
    const float* __restrict__ pf1,
    const float* __restrict__ pf2,
    const int* __restrict__ map,
    float* __restrict__ out)
{
    const int g   = blockIdx.y;           // plane-group: channels 4g..4g+3
    const int zb  = blockIdx.z;           // bin*B_ + b
    const int bin = zb >> 2;
    const int b   = zb & 3;

    const int cell = blockIdx.x * 1024 + threadIdx.x * 4;
    if (cell >= CELLS_) return;

    const float* __restrict__ pf = (bin == 0) ? pf0 : (bin == 1) ? pf1 : pf2;

    const int* m = map + (size_t)bin * MAP_BIN_ + (size_t)b * CELLS_ + cell;
    vint4 idx = *(const vint4*)m;

    const bool v0 = idx.x >= 0, v1 = idx.y >= 0, v2 = idx.z >= 0, v3 = idx.w >= 0;
    // Clamp invalid to row 0: always-safe address, unconditional 16B loads
    // of this block's 4 channels (bytes [16g, 16g+16) of the row).
    const vfloat4 x0 = *(const vfloat4*)(pf + (size_t)(v0 ? idx.x : 0) * C_ + 4 * g);
    const vfloat4 x1 = *(const vfloat4*)(pf + (size_t)(v1 ? idx.y : 0) * C_ + 4 * g);
    const vfloat4 x2 = *(const vfloat4*)(pf + (size_t)(v2 ? idx.z : 0) * C_ + 4 * g);
    const vfloat4 x3 = *(const vfloat4*)(pf + (size_t)(v3 ? idx.w : 0) * C_ + 4 * g);

    float* o = out + (size_t)bin * BIN_STRIDE_ + (size_t)b * BATCH_STRIDE_ + cell;

#pragma unroll
    for (int q = 0; q < 4; ++q) {
        vfloat4 w;
        w.x = v0 ? x0[q] : 0.0f;
        w.y = v1 ? x1[q] : 0.0f;
        w.z = v2 ? x2[q] : 0.0f;
        w.w = v3 ? x3[q] : 0.0f;
        *(vfloat4*)(o + (size_t)(4 * g + q) * PLANE_) = w;
    }
}

extern "C" void kernel_launch(void* const* d_in, const int* in_sizes, int n_in,
                              void* d_out, int out_size, void* d_ws, size_t ws_size,
                              hipStream_t stream) {
    const float* pf0 = (const float*)d_in[0];
    const int*   co0 = (const int*)d_in[1];
    const float* pf1 = (const float*)d_in[2];
    const int*   co1 = (const int*)d_in[3];
    const float* pf2 = (const float*)d_in[4];
    const int*   co2 = (const int*)d_in[5];
    float* out = (float*)d_out;

    const int npil = in_sizes[1] / 4;   // rows in coords (B*P_PER)

    int* map = (int*)d_ws;
    const size_t map_bytes = 3 * MAP_BIN_ * sizeof(int);

    // init map to -1 (0xFFFFFFFF) — ~10 MB, ~2 us
    (void)hipMemsetAsync(map, 0xFF, map_bytes, stream);

    dim3 g1((npil + 255) / 256, 3, 1);
    scatter_idx_kernel<<<g1, 256, 0, stream>>>(co0, co1, co2, map, npil);

    // x: 210 cell-chunks (fastest -> dense write frontier), y: 16 plane-
    // groups, z: 12 (bin,b) pairs. 40320 blocks, 4 loads + 4 stores/thread.
    dim3 g2((CELLS_ + 1023) / 1024, C_ / 4, 3 * B_);
    gather_split_kernel<<<g2, 256, 0, stream>>>(pf0, pf1, pf2, map, out);
}